// Round 1
// baseline (241.468 us; speedup 1.0000x reference)
//
#include <hip/hip_runtime.h>

// B=2, T=2048, C=1024, H=16, D=64
// qkv row-major [4096, 3072]; y row-major [4096, 1024]; out fp32 [4096,1024]

typedef _Float16 h8 __attribute__((ext_vector_type(8)));
typedef _Float16 h4 __attribute__((ext_vector_type(4)));
typedef float f4 __attribute__((ext_vector_type(4)));

#define GLD_LDS16(g, l)                                                              \
  __builtin_amdgcn_global_load_lds((const __attribute__((address_space(1))) void*)(g), \
                                   (__attribute__((address_space(3))) void*)(l), 16, 0, 0)

__global__ __launch_bounds__(256) void f32_to_f16_kernel(const float* __restrict__ in,
                                                         _Float16* __restrict__ out, int n4) {
  int i = blockIdx.x * 256 + threadIdx.x;
  if (i < n4) {
    f4 v = *(const f4*)(in + (size_t)i * 4);
    h4 o;
    for (int j = 0; j < 4; ++j) o[j] = (_Float16)v[j];
    *(h4*)(out + (size_t)i * 4) = o;
  }
}

// C[M,N] = A[M,K] @ B[N,K]^T, fp16 in, fp32 accum. 128x128 tile, BK=32, 4 waves (2x2).
template <typename OutT>
__global__ __launch_bounds__(256) void gemm_nt_kernel(const _Float16* __restrict__ A,
                                                      const _Float16* __restrict__ B,
                                                      OutT* __restrict__ C,
                                                      int M, int N, int K) {
  __shared__ _Float16 As[128 * 32];
  __shared__ _Float16 Bs[128 * 32];
  const int tid = threadIdx.x;
  const int wave = tid >> 6, lane = tid & 63;
  const int wm = wave >> 1, wn = wave & 1;
  const int m0 = blockIdx.y * 128, n0 = blockIdx.x * 128;

  f4 acc[4][4] = {};

  for (int k0 = 0; k0 < K; k0 += 32) {
    __syncthreads();  // protect LDS reuse across iterations
    for (int r = 0; r < 2; ++r) {
      int cb = r * 256 + wave * 64;         // wave-uniform 16B-chunk base
      int chunk = cb + lane;                // this lane's chunk
      int row = chunk >> 2;                 // 4 chunks (32 halves) per row
      int col = (chunk & 3) * 8;
      GLD_LDS16(A + (size_t)(m0 + row) * K + k0 + col, As + cb * 8);
      GLD_LDS16(B + (size_t)(n0 + row) * K + k0 + col, Bs + cb * 8);
    }
    __syncthreads();  // vmcnt drain + visibility
    h8 af[4], bf[4];
    const int kk = (lane >> 4) * 8;
    for (int mi = 0; mi < 4; ++mi)
      af[mi] = *(const h8*)(As + (wm * 64 + mi * 16 + (lane & 15)) * 32 + kk);
    for (int ni = 0; ni < 4; ++ni)
      bf[ni] = *(const h8*)(Bs + (wn * 64 + ni * 16 + (lane & 15)) * 32 + kk);
    for (int mi = 0; mi < 4; ++mi)
      for (int ni = 0; ni < 4; ++ni)
        acc[mi][ni] = __builtin_amdgcn_mfma_f32_16x16x32_f16(af[mi], bf[ni], acc[mi][ni], 0, 0, 0);
  }
  for (int mi = 0; mi < 4; ++mi)
    for (int ni = 0; ni < 4; ++ni)
      for (int i = 0; i < 4; ++i) {
        int m = m0 + wm * 64 + mi * 16 + (lane >> 4) * 4 + i;
        int n = n0 + wn * 64 + ni * 16 + (lane & 15);
        C[(size_t)m * N + n] = (OutT)acc[mi][ni][i];
      }
}

// Fused penalized attention. Grid = 512 blocks: bh (32) x pair (16).
// Each block processes q-tiles {pair, 31-pair} -> exactly 33 k-tile iters (balanced).
__global__ __launch_bounds__(256) void attn_kernel(const _Float16* __restrict__ qkv,
                                                   _Float16* __restrict__ yh) {
  __shared__ _Float16 Qs[64 * 72];   // [qrow][d], pre-scaled by 1/8
  __shared__ _Float16 Ks[64 * 72];   // [krow][d]
  __shared__ _Float16 Vt[64 * 72];   // [d][krow] (transposed)
  __shared__ _Float16 Ws[64 * 72];   // softmax weights [qrow][krow]
  __shared__ float Pb[64 * 66];      // fp32 scores / local logits
  __shared__ float segsum[64 * 4];
  __shared__ float segmax[64 * 4];
  __shared__ float wsums[64 * 4];
  __shared__ float m_arr[64], l_arr[64], c_arr[64], a_arr[64];

  const int tid = threadIdx.x;
  const int wave = tid >> 6, lane = tid & 63;
  const int bh = blockIdx.x >> 4, pair = blockIdx.x & 15;
  const int b = bh >> 4, h = bh & 15;
  const size_t base = (size_t)b * 2048 * 3072 + h * 64;

  for (int qsel = 0; qsel < 2; ++qsel) {
    const int qt = qsel ? (31 - pair) : pair;
    __syncthreads();  // prior q-tile fully consumed (y-store read l_arr)
    if (tid < 64) { m_arr[tid] = -1e30f; l_arr[tid] = 0.f; c_arr[tid] = 0.f; }
    // load Q tile, scaled by 1/sqrt(D)=0.125 (exact in fp16)
    for (int j = 0; j < 2; ++j) {
      int chunk = tid + 256 * j;
      int row = chunk >> 3, c8 = chunk & 7;
      h8 q = *(const h8*)(qkv + base + (size_t)(qt * 64 + row) * 3072 + c8 * 8);
      for (int e = 0; e < 8; ++e) q[e] = q[e] * (_Float16)0.125f;
      *(h8*)(Qs + row * 72 + c8 * 8) = q;
    }
    f4 Oacc[4] = {};

    for (int kt = 0; kt <= qt; ++kt) {
      __syncthreads();  // B1: prev iteration's MFMA reads of Ks/Vt/Ws done; Qs/state visible
      // K tile, row-major
      for (int j = 0; j < 2; ++j) {
        int chunk = tid + 256 * j;
        int row = chunk >> 3, c8 = chunk & 7;
        h8 kv = *(const h8*)(qkv + base + (size_t)(kt * 64 + row) * 3072 + 1024 + c8 * 8);
        *(h8*)(Ks + row * 72 + c8 * 8) = kv;
      }
      // V tile transposed: lane = d (coalesced 128B per t), wave = t-quarter; packed b128 writes
      {
        const _Float16* vg = qkv + base + 2048 + lane;
        h8 v0, v1;
        for (int j = 0; j < 8; ++j) v0[j] = vg[(size_t)(kt * 64 + wave * 16 + j) * 3072];
        for (int j = 0; j < 8; ++j) v1[j] = vg[(size_t)(kt * 64 + wave * 16 + 8 + j) * 3072];
        *(h8*)(Vt + lane * 72 + wave * 16) = v0;
        *(h8*)(Vt + lane * 72 + wave * 16 + 8) = v1;
      }
      __syncthreads();  // B2
      // P = Qs @ Ks^T -> Pb (wave w owns rows [16w,16w+16))
      {
        f4 pacc[4] = {};
        for (int ks = 0; ks < 2; ++ks) {
          h8 af = *(const h8*)(Qs + (16 * wave + (lane & 15)) * 72 + ks * 32 + (lane >> 4) * 8);
          for (int ni = 0; ni < 4; ++ni) {
            h8 bf = *(const h8*)(Ks + (16 * ni + (lane & 15)) * 72 + ks * 32 + (lane >> 4) * 8);
            pacc[ni] = __builtin_amdgcn_mfma_f32_16x16x32_f16(af, bf, pacc[ni], 0, 0, 0);
          }
        }
        for (int ni = 0; ni < 4; ++ni)
          for (int i = 0; i < 4; ++i)
            Pb[(16 * wave + (lane >> 4) * 4 + i) * 66 + 16 * ni + (lane & 15)] = pacc[ni][i];
      }
      __syncthreads();  // B3
      // Pass A: per (row=lane, seg=wave): sigmoid, in-segment exclusive prefix, local logit+max
      {
        const int r = lane, seg = wave;
        const bool diag = (kt == qt);
        float run = 0.f, smax = -1e30f;
        for (int c = seg * 16; c < seg * 16 + 16; ++c) {
          float p = Pb[r * 66 + c];
          bool valid = (!diag) || (c <= r);
          float Ll = valid ? (p + run) : -1e30f;
          float s = valid ? __builtin_amdgcn_rcpf(1.f + __expf(-p)) : 0.f;
          Pb[r * 66 + c] = Ll;  // overwrite with local-prefixed logit
          run += s;
          smax = fmaxf(smax, Ll);
        }
        segsum[r * 4 + seg] = run;
        segmax[r * 4 + seg] = smax;
      }
      __syncthreads();  // B4
      // Pass B: row max / weights (redundant m_new per thread from shared partials)
      {
        const int r = lane, seg = wave;
        float mo = m_arr[r];
        float mn = mo, p0 = c_arr[r], pre = c_arr[r];
        for (int s = 0; s < 4; ++s) {
          if (s == seg) pre = p0;
          mn = fmaxf(mn, segmax[r * 4 + s] + p0);
          p0 += segsum[r * 4 + s];
        }
        h8 w0, w1;
        float wsum = 0.f;
        for (int c = 0; c < 8; ++c) {
          float w = __expf(Pb[r * 66 + seg * 16 + c] + pre - mn);
          w0[c] = (_Float16)w; wsum += w;
        }
        for (int c = 0; c < 8; ++c) {
          float w = __expf(Pb[r * 66 + seg * 16 + 8 + c] + pre - mn);
          w1[c] = (_Float16)w; wsum += w;
        }
        *(h8*)(Ws + r * 72 + seg * 16) = w0;
        *(h8*)(Ws + r * 72 + seg * 16 + 8) = w1;
        wsums[r * 4 + seg] = wsum;
      }
      __syncthreads();  // B5
      if (tid < 64) {  // per-row state update
        const int r = tid;
        float mo = m_arr[r];
        float mn = mo, p0 = c_arr[r];
        for (int s = 0; s < 4; ++s) {
          mn = fmaxf(mn, segmax[r * 4 + s] + p0);
          p0 += segsum[r * 4 + s];
        }
        float al = __expf(mo - mn);
        l_arr[r] = l_arr[r] * al + (wsums[r*4] + wsums[r*4+1] + wsums[r*4+2] + wsums[r*4+3]);
        c_arr[r] += segsum[r*4] + segsum[r*4+1] + segsum[r*4+2] + segsum[r*4+3];
        m_arr[r] = mn;
        a_arr[r] = al;
      }
      __syncthreads();  // B6
      // O = O*alpha + Ws @ Vt^T(layout)  (wave w owns rows [16w,16w+16) x all 64 d)
      {
        float al[4];
        for (int i = 0; i < 4; ++i) al[i] = a_arr[16 * wave + (lane >> 4) * 4 + i];
        for (int ni = 0; ni < 4; ++ni)
          for (int i = 0; i < 4; ++i) Oacc[ni][i] *= al[i];
        for (int ks = 0; ks < 2; ++ks) {
          h8 af = *(const h8*)(Ws + (16 * wave + (lane & 15)) * 72 + ks * 32 + (lane >> 4) * 8);
          for (int ni = 0; ni < 4; ++ni) {
            h8 bf = *(const h8*)(Vt + (16 * ni + (lane & 15)) * 72 + ks * 32 + (lane >> 4) * 8);
            Oacc[ni] = __builtin_amdgcn_mfma_f32_16x16x32_f16(af, bf, Oacc[ni], 0, 0, 0);
          }
        }
      }
    }  // kt
    // y = O / l  -> yh[(b*T+t)*1024 + h*64 + d]
    for (int ni = 0; ni < 4; ++ni)
      for (int i = 0; i < 4; ++i) {
        int row = 16 * wave + (lane >> 4) * 4 + i;
        int t = qt * 64 + row;
        float yv = Oacc[ni][i] * __builtin_amdgcn_rcpf(l_arr[row]);
        yh[((size_t)(b * 2048 + t)) * 1024 + h * 64 + 16 * ni + (lane & 15)] = (_Float16)yv;
      }
  }  // qsel
}

extern "C" void kernel_launch(void* const* d_in, const int* in_sizes, int n_in,
                              void* d_out, int out_size, void* d_ws, size_t ws_size,
                              hipStream_t stream) {
  const float* x  = (const float*)d_in[0];   // [2,2048,1024]
  const float* Wa = (const float*)d_in[1];   // [3072,1024]
  const float* Wp = (const float*)d_in[2];   // [1024,1024]
  float* out = (float*)d_out;                // [4096,1024] fp32

  char* ws = (char*)d_ws;                    // 48 MB layout
  _Float16* xh   = (_Float16*)(ws);                    //  8 MB
  _Float16* wah  = (_Float16*)(ws + 8388608);          //  6 MB
  _Float16* wph  = (_Float16*)(ws + 14680064);         //  2 MB
  _Float16* qkvh = (_Float16*)(ws + 16777216);         // 24 MB
  _Float16* yh   = (_Float16*)(ws + 41943040);         //  8 MB

  f32_to_f16_kernel<<<4096, 256, 0, stream>>>(x,  xh,  4194304 / 4);
  f32_to_f16_kernel<<<3072, 256, 0, stream>>>(Wa, wah, 3145728 / 4);
  f32_to_f16_kernel<<<1024, 256, 0, stream>>>(Wp, wph, 1048576 / 4);

  gemm_nt_kernel<_Float16><<<dim3(24, 32), 256, 0, stream>>>(xh, wah, qkvh, 4096, 3072, 1024);
  attn_kernel<<<512, 256, 0, stream>>>(qkvh, yh);
  gemm_nt_kernel<float><<<dim3(8, 32), 256, 0, stream>>>(yh, wph, out, 4096, 1024, 1024);
}